// Round 18
// baseline (626.367 us; speedup 1.0000x reference)
//
#include <hip/hip_runtime.h>

// SLAYER 3-layer CUBA SNN — i8 3-plane MFMA GEMM + fused leaky-IF scan.
// R18 = R17 (XCD-aware remap, 512-thr, 128m x 64o, kc=128B — wall 214.2,
// L1 52.9 us, FETCH 72->41 MB) + occupancy doubled: launch_bounds(512,8).
// VGPR_Count measured 52 <= 64 (8-waves/EU class) and LDS 4 x 40,960 B =
// exactly 160 KiB -> 4 blocks/CU resident (was 2), doubling the waves that
// hide the per-chunk glds16 drain (m114: independent blocks co-schedule).
// XCD remap: b = (bx&7)*8 + (by&7), o = (bx>>3)*8 + (by>>3) -> each XCD
// owns 8 b-tiles = 2 MB of A (L2-resident) + cross-layer dirty-L2 reuse.
// W = 2^-8*q1 + 2^-15*q2 + 2^-22*q3 (i8 planes, exact fp32 residuals);
// Z = S1*D1 + S2*D2 + S3*D3, i32 MFMA accum exact; per-weight err <= 2^-23
// (absmax 0.0 R12-R17). Spikes exact in i8.
// Frag geometry (proven conflict-free): fr=lane&15, q=lane>>4, b128 frags,
// slot swizzle phys = row*8 + (u0 ^ (row&7)), u0 = hh*4 + q.
// Layout m = b*128 + t: block holds full Z[t][o] history -> in-LDS scan.

typedef unsigned short ushort_t;
typedef unsigned int uint_t;
typedef unsigned char uchar_t;
typedef int i32x4 __attribute__((ext_vector_type(4)));

#define S1F 0.00390625f             // 2^-8
#define S2F 3.0517578125e-5f        // 2^-15
#define S3F 2.384185791015625e-7f   // 2^-22

__device__ __forceinline__ void glds16(const uchar_t* g, uchar_t* l) {
  __builtin_amdgcn_global_load_lds(
      (const __attribute__((address_space(1))) uint_t*)g,
      (__attribute__((address_space(3))) uint_t*)l, 16, 0, 0);
}

// ---- prep: W1/W2 -> 3 i8 planes (blocks 0..3071) + spike transpose ---------
__global__ __launch_bounds__(256) void prep(const float* __restrict__ W1,
                                            const float* __restrict__ W2,
                                            const float* __restrict__ spike,
                                            char* __restrict__ w1q1,
                                            char* __restrict__ w1q2,
                                            char* __restrict__ w1q3,
                                            char* __restrict__ w2q1,
                                            char* __restrict__ w2q2,
                                            char* __restrict__ w2q3,
                                            uchar_t* __restrict__ A1) {
  const int tid = threadIdx.x;
  if (blockIdx.x < 3072) {
    const float* W;
    char *p1, *p2, *p3;
    size_t e0;
    if (blockIdx.x < 2048) {
      W = W1; p1 = w1q1; p2 = w1q2; p3 = w1q3;
      e0 = (size_t)blockIdx.x * 1024 + tid * 4;
    } else {
      W = W2; p1 = w2q1; p2 = w2q2; p3 = w2q3;
      e0 = (size_t)(blockIdx.x - 2048) * 1024 + tid * 4;
    }
    float4 w = *(const float4*)(W + e0);
    char4 c1, c2, c3;
    float q, r;
#define QUANT(comp, f1, f2, f3)                    \
    q = rintf((comp) * 256.0f);  f1 = (char)(int)q; \
    r = (comp) - q * S1F;                           \
    q = rintf(r * 32768.0f);     f2 = (char)(int)q; \
    r = r - q * S2F;                                \
    q = rintf(r * 4194304.0f);   f3 = (char)(int)q;
    QUANT(w.x, c1.x, c2.x, c3.x)
    QUANT(w.y, c1.y, c2.y, c3.y)
    QUANT(w.z, c1.z, c2.z, c3.z)
    QUANT(w.w, c1.w, c2.w, c3.w)
#undef QUANT
    *(char4*)(p1 + e0) = c1;
    *(char4*)(p2 + e0) = c2;
    *(char4*)(p3 + e0) = c3;
    return;
  }
  // spike [b][i][t] f32 -> A1 [b*128+t][i] i8 (0/1)
  __shared__ uchar_t lds8[128 * 132];  // [i][t] padded
  const int bid = blockIdx.x - 3072;   // 0..1023
  const int b = bid >> 4;
  const int i0 = (bid & 15) * 128;
#pragma unroll
  for (int it = 0; it < 16; ++it) {
    int p = it * 256 + tid;
    int i = p >> 5, tg = (p & 31) * 4;
    float4 v = *(const float4*)(spike + ((size_t)b * 2048 + i0 + i) * 128 + tg);
    uint_t pk = (v.x != 0.0f ? 1u : 0u) | (v.y != 0.0f ? 1u : 0u) << 8 |
                (v.z != 0.0f ? 1u : 0u) << 16 | (v.w != 0.0f ? 1u : 0u) << 24;
    *(uint_t*)(lds8 + i * 132 + tg) = pk;
  }
  __syncthreads();
#pragma unroll
  for (int it = 0; it < 16; ++it) {
    int p = it * 256 + tid;
    int t = p >> 5, jw = p & 31;  // output uint (4 i-bytes)
    uint_t u = (uint_t)lds8[(4 * jw + 0) * 132 + t] |
               ((uint_t)lds8[(4 * jw + 1) * 132 + t] << 8) |
               ((uint_t)lds8[(4 * jw + 2) * 132 + t] << 16) |
               ((uint_t)lds8[(4 * jw + 3) * 132 + t] << 24);
    *(uint_t*)(A1 + (size_t)(b * 128 + t) * 2048 + i0 + jw * 4) = u;
  }
}

// ---- fused GEMM (128m x 64o, kc=128B, 512 thr, i8 3-plane) + scan ----------
// XCD-aware tile assignment; 8 waves/EU -> 4 blocks/CU (LDS exactly 160 KiB).
__global__ __launch_bounds__(512, 8)
void gemm_scan(const uchar_t* __restrict__ A, const char* __restrict__ Q1,
               const char* __restrict__ Q2, const char* __restrict__ Q3,
               uchar_t* __restrict__ S, int K) {
  __shared__ float smemf[10240];     // 40,960 B staging; Zt overlay 33,280 B
  uchar_t* sA = (uchar_t*)smemf;     // A: slots 0..1023; B plane p: 1024+p*512
  float* Zt = smemf;                 // [128 t][65] epilogue overlay

  const int tid = threadIdx.x;
  const int wave = tid >> 6, lane = tid & 63;
  // XCD-aware remap (grid 16 x 64): XCD ~= bx%8 owns b-tiles [8c, 8c+8)
  const int bt = (blockIdx.x & 7) * 8 + (blockIdx.y & 7);          // 0..63
  const int ot = (blockIdx.x >> 3) * 8 + (blockIdx.y >> 3);        // 0..15
  const int m0 = bt * 128;
  const int o0 = ot * 64;
  const int qm = wave >> 2, qn = wave & 3;
  const int fr = lane & 15, q = lane >> 4;

  i32x4 acc[4][3];
#pragma unroll
  for (int i = 0; i < 4; ++i)
#pragma unroll
    for (int p = 0; p < 3; ++p) acc[i][p] = (i32x4){0, 0, 0, 0};

  // staging: 2560 slots (A 1024 + B 3x512), exactly 5 rounds of 512 threads.
  const char* qplanes[3] = {Q1, Q2, Q3};
  const uchar_t* gsrc[5];
  uchar_t* ldst[5];
#pragma unroll
  for (int it = 0; it < 5; ++it) {
    int s = it * 512 + tid;
    ldst[it] = sA + (size_t)(it * 512 + wave * 64) * 16;
    if (s < 1024) {
      int row = s >> 3;
      int u0 = (s & 7) ^ (row & 7);
      gsrc[it] = A + (size_t)(m0 + row) * K + u0 * 16;
    } else {
      int t2 = s - 1024;
      int p = t2 >> 9, w = t2 & 511;
      int row = w >> 3;
      int u0 = (w & 7) ^ (row & 7);
      gsrc[it] = (const uchar_t*)qplanes[p] + (size_t)(o0 + row) * K + u0 * 16;
    }
  }

  // frag LDS byte offsets per k-half hh: u0 = hh*4 + q
  int aoff[4][2], boff[3][2];  // [p][hh]
#pragma unroll
  for (int i = 0; i < 4; ++i) {
    int row = qm * 64 + i * 16 + fr;
#pragma unroll
    for (int hh = 0; hh < 2; ++hh)
      aoff[i][hh] = (row * 8 + ((hh * 4 + q) ^ (row & 7))) * 16;
  }
  {
    int row = qn * 16 + fr;
#pragma unroll
    for (int hh = 0; hh < 2; ++hh) {
      int rel = row * 8 + ((hh * 4 + q) ^ (row & 7));
#pragma unroll
      for (int p = 0; p < 3; ++p)
        boff[p][hh] = (1024 + p * 512 + rel) * 16;
    }
  }

  for (int kc = 0; kc < K; kc += 128) {
#pragma unroll
    for (int it = 0; it < 5; ++it) glds16(gsrc[it] + kc, ldst[it]);
    __syncthreads();

#pragma unroll
    for (int hh = 0; hh < 2; ++hh) {
      i32x4 af[4], bq[3];
#pragma unroll
      for (int i = 0; i < 4; ++i) af[i] = *(const i32x4*)(sA + aoff[i][hh]);
#pragma unroll
      for (int p = 0; p < 3; ++p) bq[p] = *(const i32x4*)(sA + boff[p][hh]);
#pragma unroll
      for (int p = 0; p < 3; ++p)
#pragma unroll
        for (int i = 0; i < 4; ++i)
          acc[i][p] = __builtin_amdgcn_mfma_i32_16x16x64_i8(af[i], bq[p], acc[i][p], 0, 0, 0);
    }
    __syncthreads();
  }

  // combine planes -> fp32, write Z-tile (C/D: col=fr, row=q*4+rr)
#pragma unroll
  for (int i = 0; i < 4; ++i)
#pragma unroll
    for (int rr = 0; rr < 4; ++rr) {
      int t = qm * 64 + i * 16 + q * 4 + rr;
      float z = (float)acc[i][0][rr] * S1F + (float)acc[i][1][rr] * S2F +
                (float)acc[i][2][rr] * S3F;
      Zt[t * 65 + qn * 16 + fr] = z;
    }
  __syncthreads();

  // fused leaky-IF scan: thread tid<64 owns o-column (o0+tid)
  if (tid < 64) {
#pragma clang fp contract(off)
    float cur = 0.0f, vol = 0.0f;
    const int o = o0 + tid;
    for (int t = 0; t < 128; ++t) {
      float z = Zt[t * 65 + tid];
      cur = cur * 0.7f;
      cur = cur + z;
      vol = vol * 0.2f;
      vol = vol + cur;
      float v = vol - 1.0f;
      float s = (v >= 0.0f) ? 1.0f : 0.0f;
      vol = vol * (1.0f - s);
      S[(size_t)(m0 + t) * 1024 + o] = (v >= 0.0f) ? 1u : 0u;
    }
  }
}

// ---------- layer 3 fused: per-b dense (O=2, fp32) + scan + output ----------
__global__ __launch_bounds__(256) void gemm3_scan(const uchar_t* __restrict__ X,
                                                  const float* __restrict__ W3,
                                                  float* __restrict__ out) {
  __shared__ float w3s[2048];
  __shared__ float z3[256];  // [t*2 + o]
  __shared__ float sp[256];  // [o*128 + t]
  const int tid = threadIdx.x;
  const int b = blockIdx.x;
  for (int i = tid; i < 2048; i += 256) w3s[i] = W3[i];
  __syncthreads();
  const int wave = tid >> 6, lane = tid & 63;
  for (int tt = 0; tt < 32; ++tt) {
    int t = wave * 32 + tt;
    const uint4* rp = (const uint4*)(X + (size_t)(b * 128 + t) * 1024);
    uint4 v = rp[lane];
    float s0 = 0.0f, s1 = 0.0f;
    const uint_t uw[4] = {v.x, v.y, v.z, v.w};
#pragma unroll
    for (int wq = 0; wq < 4; ++wq)
#pragma unroll
      for (int c = 0; c < 4; ++c) {
        float x = (float)((uw[wq] >> (8 * c)) & 1u);
        int i0 = lane * 16 + wq * 4 + c;
        s0 = fmaf(x, w3s[i0], s0);
        s1 = fmaf(x, w3s[1024 + i0], s1);
      }
#pragma unroll
    for (int off = 32; off > 0; off >>= 1) {
      s0 += __shfl_down(s0, off);
      s1 += __shfl_down(s1, off);
    }
    if (lane == 0) {
      z3[t * 2] = s0;
      z3[t * 2 + 1] = s1;
    }
  }
  __syncthreads();
  if (tid < 2) {
#pragma clang fp contract(off)
    float cur = 0.0f, vol = 0.0f;
    for (int t = 0; t < 128; ++t) {
      float z = z3[t * 2 + tid];
      cur = cur * 0.7f;
      cur = cur + z;
      vol = vol * 0.2f;
      vol = vol + cur;
      float v = vol - 1.0f;
      float s = (v >= 0.0f) ? 1.0f : 0.0f;
      vol = vol * (1.0f - s);
      sp[tid * 128 + t] = s;
    }
  }
  __syncthreads();
  out[b * 256 + tid] = sp[tid];
}

extern "C" void kernel_launch(void* const* d_in, const int* in_sizes, int n_in,
                              void* d_out, int out_size, void* d_ws, size_t ws_size,
                              hipStream_t stream) {
  const float* spike = (const float*)d_in[0];  // [64, 2048, 128]
  const float* W1 = (const float*)d_in[1];     // [1024, 2048]
  const float* W2 = (const float*)d_in[2];     // [1024, 1024]
  const float* W3 = (const float*)d_in[3];     // [2, 1024]
  float* out = (float*)d_out;                  // [64, 2, 128]

  char* ws = (char*)d_ws;
  const size_t MB = 1024 * 1024;
  uchar_t* A1 = (uchar_t*)ws;                  // 16 MB [8192][2048] i8
  uchar_t* S2 = (uchar_t*)(ws + 16 * MB);      // 8 MB  [8192][1024] i8
  uchar_t* S3 = (uchar_t*)(ws + 24 * MB);      // 8 MB
  char* w1q1 = ws + 32 * MB;                   // 2 MB each
  char* w1q2 = ws + 34 * MB;
  char* w1q3 = ws + 36 * MB;
  char* w2q1 = ws + 38 * MB;                   // 1 MB each
  char* w2q2 = ws + 39 * MB;
  char* w2q3 = ws + 40 * MB;

  // blocks 0..2047: W1 quant; 2048..3071: W2 quant; 3072..4095: transpose
  prep<<<4096, 256, 0, stream>>>(W1, W2, spike, w1q1, w1q2, w1q3, w2q1, w2q2,
                                 w2q3, A1);
  // L1: M=8192 (b*128+t), K=2048 B, O=1024 (16 o-tiles of 64), XCD-remapped
  gemm_scan<<<dim3(16, 64), 512, 0, stream>>>(A1, w1q1, w1q2, w1q3, S2, 2048);
  // L2: K=1024 B, XCD-remapped
  gemm_scan<<<dim3(16, 64), 512, 0, stream>>>(S2, w2q1, w2q2, w2q3, S3, 1024);
  // L3 + final scan + output
  gemm3_scan<<<64, 256, 0, stream>>>(S3, W3, out);
}

// Round 19
// 213.767 us; speedup vs baseline: 2.9301x; 2.9301x over previous
//
#include <hip/hip_runtime.h>

// SLAYER 3-layer CUBA SNN — i8 3-plane MFMA GEMM + fused leaky-IF scan.
// R19 = R17 verbatim (best: 214.2 us, absmax 0.0). R18's launch_bounds(512,8)
// forced the 32-VGPR class -> total spill (WRITE 872 MB, 626 us). (512,4) is
// the max legal occupancy for this kernel's 52 VGPRs. FINAL CONFIG:
// - i8 3-plane weights: W = 2^-8*q1 + 2^-15*q2 + 2^-22*q3 (exact fp32
//   residuals, per-weight err <= 2^-23); spikes exact in i8; i32 MFMA accum
//   exact -> absmax 0.0 across R12-R17.
// - mfma_i32_16x16x64_i8, frag geometry fr=lane&15, q=lane>>4 (conflict-free),
//   slot swizzle phys = row*8 + (u0 ^ (row&7)).
// - 512-thr blocks, 128m x 64o tile, kc=128B, stage->barrier->MFMA->barrier.
// - XCD-aware remap: bt=(bx&7)*8+(by&7), ot=(bx>>3)*8+(by>>3) -> each XCD
//   owns 2 MB of A (L2-resident; FETCH 72->41 MB, L1 68->53 us).
// - Fused leaky-IF scan epilogue (m = b*128 + t layout), fused L3+scan.

typedef unsigned short ushort_t;
typedef unsigned int uint_t;
typedef unsigned char uchar_t;
typedef int i32x4 __attribute__((ext_vector_type(4)));

#define S1F 0.00390625f             // 2^-8
#define S2F 3.0517578125e-5f        // 2^-15
#define S3F 2.384185791015625e-7f   // 2^-22

__device__ __forceinline__ void glds16(const uchar_t* g, uchar_t* l) {
  __builtin_amdgcn_global_load_lds(
      (const __attribute__((address_space(1))) uint_t*)g,
      (__attribute__((address_space(3))) uint_t*)l, 16, 0, 0);
}

// ---- prep: W1/W2 -> 3 i8 planes (blocks 0..3071) + spike transpose ---------
__global__ __launch_bounds__(256) void prep(const float* __restrict__ W1,
                                            const float* __restrict__ W2,
                                            const float* __restrict__ spike,
                                            char* __restrict__ w1q1,
                                            char* __restrict__ w1q2,
                                            char* __restrict__ w1q3,
                                            char* __restrict__ w2q1,
                                            char* __restrict__ w2q2,
                                            char* __restrict__ w2q3,
                                            uchar_t* __restrict__ A1) {
  const int tid = threadIdx.x;
  if (blockIdx.x < 3072) {
    const float* W;
    char *p1, *p2, *p3;
    size_t e0;
    if (blockIdx.x < 2048) {
      W = W1; p1 = w1q1; p2 = w1q2; p3 = w1q3;
      e0 = (size_t)blockIdx.x * 1024 + tid * 4;
    } else {
      W = W2; p1 = w2q1; p2 = w2q2; p3 = w2q3;
      e0 = (size_t)(blockIdx.x - 2048) * 1024 + tid * 4;
    }
    float4 w = *(const float4*)(W + e0);
    char4 c1, c2, c3;
    float q, r;
#define QUANT(comp, f1, f2, f3)                    \
    q = rintf((comp) * 256.0f);  f1 = (char)(int)q; \
    r = (comp) - q * S1F;                           \
    q = rintf(r * 32768.0f);     f2 = (char)(int)q; \
    r = r - q * S2F;                                \
    q = rintf(r * 4194304.0f);   f3 = (char)(int)q;
    QUANT(w.x, c1.x, c2.x, c3.x)
    QUANT(w.y, c1.y, c2.y, c3.y)
    QUANT(w.z, c1.z, c2.z, c3.z)
    QUANT(w.w, c1.w, c2.w, c3.w)
#undef QUANT
    *(char4*)(p1 + e0) = c1;
    *(char4*)(p2 + e0) = c2;
    *(char4*)(p3 + e0) = c3;
    return;
  }
  // spike [b][i][t] f32 -> A1 [b*128+t][i] i8 (0/1)
  __shared__ uchar_t lds8[128 * 132];  // [i][t] padded
  const int bid = blockIdx.x - 3072;   // 0..1023
  const int b = bid >> 4;
  const int i0 = (bid & 15) * 128;
#pragma unroll
  for (int it = 0; it < 16; ++it) {
    int p = it * 256 + tid;
    int i = p >> 5, tg = (p & 31) * 4;
    float4 v = *(const float4*)(spike + ((size_t)b * 2048 + i0 + i) * 128 + tg);
    uint_t pk = (v.x != 0.0f ? 1u : 0u) | (v.y != 0.0f ? 1u : 0u) << 8 |
                (v.z != 0.0f ? 1u : 0u) << 16 | (v.w != 0.0f ? 1u : 0u) << 24;
    *(uint_t*)(lds8 + i * 132 + tg) = pk;
  }
  __syncthreads();
#pragma unroll
  for (int it = 0; it < 16; ++it) {
    int p = it * 256 + tid;
    int t = p >> 5, jw = p & 31;  // output uint (4 i-bytes)
    uint_t u = (uint_t)lds8[(4 * jw + 0) * 132 + t] |
               ((uint_t)lds8[(4 * jw + 1) * 132 + t] << 8) |
               ((uint_t)lds8[(4 * jw + 2) * 132 + t] << 16) |
               ((uint_t)lds8[(4 * jw + 3) * 132 + t] << 24);
    *(uint_t*)(A1 + (size_t)(b * 128 + t) * 2048 + i0 + jw * 4) = u;
  }
}

// ---- fused GEMM (128m x 64o, kc=128B, 512 thr, i8 3-plane) + scan ----------
// XCD-aware tile assignment: see header comment.
__global__ __launch_bounds__(512, 4)
void gemm_scan(const uchar_t* __restrict__ A, const char* __restrict__ Q1,
               const char* __restrict__ Q2, const char* __restrict__ Q3,
               uchar_t* __restrict__ S, int K) {
  __shared__ float smemf[10240];     // 40,960 B staging; Zt overlay 33,280 B
  uchar_t* sA = (uchar_t*)smemf;     // A: slots 0..1023; B plane p: 1024+p*512
  float* Zt = smemf;                 // [128 t][65] epilogue overlay

  const int tid = threadIdx.x;
  const int wave = tid >> 6, lane = tid & 63;
  // XCD-aware remap (grid 16 x 64): XCD ~= bx%8 owns b-tiles [8c, 8c+8)
  const int bt = (blockIdx.x & 7) * 8 + (blockIdx.y & 7);          // 0..63
  const int ot = (blockIdx.x >> 3) * 8 + (blockIdx.y >> 3);        // 0..15
  const int m0 = bt * 128;
  const int o0 = ot * 64;
  const int qm = wave >> 2, qn = wave & 3;
  const int fr = lane & 15, q = lane >> 4;

  i32x4 acc[4][3];
#pragma unroll
  for (int i = 0; i < 4; ++i)
#pragma unroll
    for (int p = 0; p < 3; ++p) acc[i][p] = (i32x4){0, 0, 0, 0};

  // staging: 2560 slots (A 1024 + B 3x512), exactly 5 rounds of 512 threads.
  const char* qplanes[3] = {Q1, Q2, Q3};
  const uchar_t* gsrc[5];
  uchar_t* ldst[5];
#pragma unroll
  for (int it = 0; it < 5; ++it) {
    int s = it * 512 + tid;
    ldst[it] = sA + (size_t)(it * 512 + wave * 64) * 16;
    if (s < 1024) {
      int row = s >> 3;
      int u0 = (s & 7) ^ (row & 7);
      gsrc[it] = A + (size_t)(m0 + row) * K + u0 * 16;
    } else {
      int t2 = s - 1024;
      int p = t2 >> 9, w = t2 & 511;
      int row = w >> 3;
      int u0 = (w & 7) ^ (row & 7);
      gsrc[it] = (const uchar_t*)qplanes[p] + (size_t)(o0 + row) * K + u0 * 16;
    }
  }

  // frag LDS byte offsets per k-half hh: u0 = hh*4 + q
  int aoff[4][2], boff[3][2];  // [p][hh]
#pragma unroll
  for (int i = 0; i < 4; ++i) {
    int row = qm * 64 + i * 16 + fr;
#pragma unroll
    for (int hh = 0; hh < 2; ++hh)
      aoff[i][hh] = (row * 8 + ((hh * 4 + q) ^ (row & 7))) * 16;
  }
  {
    int row = qn * 16 + fr;
#pragma unroll
    for (int hh = 0; hh < 2; ++hh) {
      int rel = row * 8 + ((hh * 4 + q) ^ (row & 7));
#pragma unroll
      for (int p = 0; p < 3; ++p)
        boff[p][hh] = (1024 + p * 512 + rel) * 16;
    }
  }

  for (int kc = 0; kc < K; kc += 128) {
#pragma unroll
    for (int it = 0; it < 5; ++it) glds16(gsrc[it] + kc, ldst[it]);
    __syncthreads();

#pragma unroll
    for (int hh = 0; hh < 2; ++hh) {
      i32x4 af[4], bq[3];
#pragma unroll
      for (int i = 0; i < 4; ++i) af[i] = *(const i32x4*)(sA + aoff[i][hh]);
#pragma unroll
      for (int p = 0; p < 3; ++p) bq[p] = *(const i32x4*)(sA + boff[p][hh]);
#pragma unroll
      for (int p = 0; p < 3; ++p)
#pragma unroll
        for (int i = 0; i < 4; ++i)
          acc[i][p] = __builtin_amdgcn_mfma_i32_16x16x64_i8(af[i], bq[p], acc[i][p], 0, 0, 0);
    }
    __syncthreads();
  }

  // combine planes -> fp32, write Z-tile (C/D: col=fr, row=q*4+rr)
#pragma unroll
  for (int i = 0; i < 4; ++i)
#pragma unroll
    for (int rr = 0; rr < 4; ++rr) {
      int t = qm * 64 + i * 16 + q * 4 + rr;
      float z = (float)acc[i][0][rr] * S1F + (float)acc[i][1][rr] * S2F +
                (float)acc[i][2][rr] * S3F;
      Zt[t * 65 + qn * 16 + fr] = z;
    }
  __syncthreads();

  // fused leaky-IF scan: thread tid<64 owns o-column (o0+tid)
  if (tid < 64) {
#pragma clang fp contract(off)
    float cur = 0.0f, vol = 0.0f;
    const int o = o0 + tid;
    for (int t = 0; t < 128; ++t) {
      float z = Zt[t * 65 + tid];
      cur = cur * 0.7f;
      cur = cur + z;
      vol = vol * 0.2f;
      vol = vol + cur;
      float v = vol - 1.0f;
      float s = (v >= 0.0f) ? 1.0f : 0.0f;
      vol = vol * (1.0f - s);
      S[(size_t)(m0 + t) * 1024 + o] = (v >= 0.0f) ? 1u : 0u;
    }
  }
}

// ---------- layer 3 fused: per-b dense (O=2, fp32) + scan + output ----------
__global__ __launch_bounds__(256) void gemm3_scan(const uchar_t* __restrict__ X,
                                                  const float* __restrict__ W3,
                                                  float* __restrict__ out) {
  __shared__ float w3s[2048];
  __shared__ float z3[256];  // [t*2 + o]
  __shared__ float sp[256];  // [o*128 + t]
  const int tid = threadIdx.x;
  const int b = blockIdx.x;
  for (int i = tid; i < 2048; i += 256) w3s[i] = W3[i];
  __syncthreads();
  const int wave = tid >> 6, lane = tid & 63;
  for (int tt = 0; tt < 32; ++tt) {
    int t = wave * 32 + tt;
    const uint4* rp = (const uint4*)(X + (size_t)(b * 128 + t) * 1024);
    uint4 v = rp[lane];
    float s0 = 0.0f, s1 = 0.0f;
    const uint_t uw[4] = {v.x, v.y, v.z, v.w};
#pragma unroll
    for (int wq = 0; wq < 4; ++wq)
#pragma unroll
      for (int c = 0; c < 4; ++c) {
        float x = (float)((uw[wq] >> (8 * c)) & 1u);
        int i0 = lane * 16 + wq * 4 + c;
        s0 = fmaf(x, w3s[i0], s0);
        s1 = fmaf(x, w3s[1024 + i0], s1);
      }
#pragma unroll
    for (int off = 32; off > 0; off >>= 1) {
      s0 += __shfl_down(s0, off);
      s1 += __shfl_down(s1, off);
    }
    if (lane == 0) {
      z3[t * 2] = s0;
      z3[t * 2 + 1] = s1;
    }
  }
  __syncthreads();
  if (tid < 2) {
#pragma clang fp contract(off)
    float cur = 0.0f, vol = 0.0f;
    for (int t = 0; t < 128; ++t) {
      float z = z3[t * 2 + tid];
      cur = cur * 0.7f;
      cur = cur + z;
      vol = vol * 0.2f;
      vol = vol + cur;
      float v = vol - 1.0f;
      float s = (v >= 0.0f) ? 1.0f : 0.0f;
      vol = vol * (1.0f - s);
      sp[tid * 128 + t] = s;
    }
  }
  __syncthreads();
  out[b * 256 + tid] = sp[tid];
}

extern "C" void kernel_launch(void* const* d_in, const int* in_sizes, int n_in,
                              void* d_out, int out_size, void* d_ws, size_t ws_size,
                              hipStream_t stream) {
  const float* spike = (const float*)d_in[0];  // [64, 2048, 128]
  const float* W1 = (const float*)d_in[1];     // [1024, 2048]
  const float* W2 = (const float*)d_in[2];     // [1024, 1024]
  const float* W3 = (const float*)d_in[3];     // [2, 1024]
  float* out = (float*)d_out;                  // [64, 2, 128]

  char* ws = (char*)d_ws;
  const size_t MB = 1024 * 1024;
  uchar_t* A1 = (uchar_t*)ws;                  // 16 MB [8192][2048] i8
  uchar_t* S2 = (uchar_t*)(ws + 16 * MB);      // 8 MB  [8192][1024] i8
  uchar_t* S3 = (uchar_t*)(ws + 24 * MB);      // 8 MB
  char* w1q1 = ws + 32 * MB;                   // 2 MB each
  char* w1q2 = ws + 34 * MB;
  char* w1q3 = ws + 36 * MB;
  char* w2q1 = ws + 38 * MB;                   // 1 MB each
  char* w2q2 = ws + 39 * MB;
  char* w2q3 = ws + 40 * MB;

  // blocks 0..2047: W1 quant; 2048..3071: W2 quant; 3072..4095: transpose
  prep<<<4096, 256, 0, stream>>>(W1, W2, spike, w1q1, w1q2, w1q3, w2q1, w2q2,
                                 w2q3, A1);
  // L1: M=8192 (b*128+t), K=2048 B, O=1024 (16 o-tiles of 64), XCD-remapped
  gemm_scan<<<dim3(16, 64), 512, 0, stream>>>(A1, w1q1, w1q2, w1q3, S2, 2048);
  // L2: K=1024 B, XCD-remapped
  gemm_scan<<<dim3(16, 64), 512, 0, stream>>>(S2, w2q1, w2q2, w2q3, S3, 1024);
  // L3 + final scan + output
  gemm3_scan<<<64, 256, 0, stream>>>(S3, W3, out);
}